// Round 10
// baseline (67.519 us; speedup 1.0000x reference)
//
#include <hip/hip_runtime.h>

// B=8, C=21, H=512, W=512 ; gt/pred int32 ; output = scalar f32
// mean over B of tp / max(tp+fp+fn, 1e-8)
//   valid = gt != 255 ; eq = gt==pred ; gt_in = 1<=gt<21 ; pred_in = 1<=pred<21

#define N_CLASSES 21
#define IGNORE_LBL 255
#define BATCH 8
#define BPS 168                  // blocks per sample -> 1344 total (~5.25/CU, co-resident)
#define THREADS 256
#define VEC_PER_SAMPLE 1376256   // int4 per sample (21*512*512/4)
#define STRIDE (BPS * THREADS)   // 43008 int4
#define OUTER 16                 // 32 int4/thread = 16 outer x unroll2, no tail

__device__ __forceinline__ void proc4(const int4& g, const int4& p,
                                      int& tp, int& fp, int& fn) {
    const int gv[4] = {g.x, g.y, g.z, g.w};
    const int pv[4] = {p.x, p.y, p.z, p.w};
#pragma unroll
    for (int k = 0; k < 4; ++k) {
        const int gk = gv[k], pk = pv[k];
        const int valid = (gk != IGNORE_LBL);
        const int eq = (gk == pk);
        const int gin = (gk >= 1) & (gk < N_CLASSES);
        const int pin = (pk >= 1) & (pk < N_CLASSES);
        tp += eq & gin & valid;
        fp += (eq ^ 1) & pin & valid;
        fn += (eq ^ 1) & gin & valid;
    }
}

// Per-block partials WRITTEN (not atomic) to parts[b*BPS+bx] — no atomics,
// no memset, no fence. Fully overwritten every call (deterministic).
__global__ __launch_bounds__(THREADS) void iou_count_kernel(
    const int* __restrict__ gt, const int* __restrict__ pred,
    int4* __restrict__ parts) {
    const int b = blockIdx.y;
    const int4* __restrict__ g4 =
        reinterpret_cast<const int4*>(gt) + (size_t)b * VEC_PER_SAMPLE;
    const int4* __restrict__ p4 =
        reinterpret_cast<const int4*>(pred) + (size_t)b * VEC_PER_SAMPLE;

    int i = blockIdx.x * THREADS + threadIdx.x;
    int tp = 0, fp = 0, fn = 0;

    // r5-proven unroll2 structure (4 loads in flight); co-resident grid
    // means no second dispatch round / no lone-block tail.
#pragma unroll 1
    for (int o = 0; o < OUTER; ++o) {
        const int4 g0 = g4[i];
        const int4 p0 = p4[i];
        const int4 g1 = g4[i + STRIDE];
        const int4 p1 = p4[i + STRIDE];
        __builtin_amdgcn_sched_barrier(0);
        proc4(g0, p0, tp, fp, fn);
        proc4(g1, p1, tp, fp, fn);
        i += 2 * STRIDE;
    }

    // wave (64-lane) reduce
#pragma unroll
    for (int off = 32; off > 0; off >>= 1) {
        tp += __shfl_down(tp, off);
        fp += __shfl_down(fp, off);
        fn += __shfl_down(fn, off);
    }

    __shared__ int s_tp[4], s_fp[4], s_fn[4];  // 256 threads = 4 waves
    const int wave = threadIdx.x >> 6;
    const int lane = threadIdx.x & 63;
    if (lane == 0) {
        s_tp[wave] = tp;
        s_fp[wave] = fp;
        s_fn[wave] = fn;
    }
    __syncthreads();
    if (threadIdx.x == 0) {
        int t = 0, f = 0, n = 0;
#pragma unroll
        for (int w = 0; w < 4; ++w) {
            t += s_tp[w];
            f += s_fp[w];
            n += s_fn[w];
        }
        parts[b * BPS + blockIdx.x] = make_int4(t, f, n, 0);
    }
}

// 8 waves; wave w reduces sample w's 168 partials (coalesced int4 reads)
__global__ __launch_bounds__(512) void iou_final_kernel(
    const int4* __restrict__ parts, float* __restrict__ out) {
    const int w = threadIdx.x >> 6;   // sample
    const int lane = threadIdx.x & 63;

    int t = 0, f = 0, n = 0;
#pragma unroll
    for (int k = 0; k < 3; ++k) {
        const int idx = k * 64 + lane;
        if (idx < BPS) {
            const int4 v = parts[w * BPS + idx];
            t += v.x;
            f += v.y;
            n += v.z;
        }
    }
#pragma unroll
    for (int off = 32; off > 0; off >>= 1) {
        t += __shfl_down(t, off);
        f += __shfl_down(f, off);
        n += __shfl_down(n, off);
    }

    __shared__ float jac[BATCH];
    if (lane == 0) {
        const float tp = (float)t, fp = (float)f, fn = (float)n;
        jac[w] = tp / fmaxf(tp + fp + fn, 1e-8f);
    }
    __syncthreads();
    if (threadIdx.x == 0) {
        float s = 0.0f;
#pragma unroll
        for (int b = 0; b < BATCH; ++b) s += jac[b];
        out[0] = s / (float)BATCH;
    }
}

extern "C" void kernel_launch(void* const* d_in, const int* in_sizes, int n_in,
                              void* d_out, int out_size, void* d_ws, size_t ws_size,
                              hipStream_t stream) {
    const int* gt = (const int*)d_in[0];
    const int* pred = (const int*)d_in[1];
    float* out = (float*)d_out;
    int4* parts = (int4*)d_ws;  // 8*168*16 B = 21.5 KB

    dim3 grid(BPS, BATCH, 1);
    dim3 block(THREADS, 1, 1);
    iou_count_kernel<<<grid, block, 0, stream>>>(gt, pred, parts);
    iou_final_kernel<<<1, 512, 0, stream>>>(parts, out);
}

// Round 11
// 66.246 us; speedup vs baseline: 1.0192x; 1.0192x over previous
//
#include <hip/hip_runtime.h>

// B=8, C=21, H=512, W=512 ; gt/pred int32 ; output = scalar f32
// mean over B of tp / max(tp+fp+fn, 1e-8)
//   valid = gt != 255 ; eq = gt==pred ; gt_in = 1<=gt<21 ; pred_in = 1<=pred<21
//
// r9-proven configuration (64.8 us):
//  - 2048 blocks = exactly 8/CU, uniform residency (r10: non-integral hurts)
//  - unroll3 register loads (6 in flight; compiler caps ~4-6, more regresses r6)
//  - per-block partials WRITTEN to ws (atomics cost ~20us: r5 vs r9; fence ~2x: r2-r4)
//  - no memset node (parts fully overwritten every call -> deterministic)
//  - two kernels: kernel boundary is the only fence-free cross-XCD sync

#define N_CLASSES 21
#define IGNORE_LBL 255
#define BATCH 8
#define BPS 256                  // blocks per sample
#define THREADS 256
#define VEC_PER_SAMPLE 1376256   // int4 per sample (21*512*512/4)
#define STRIDE (BPS * THREADS)   // 65536 int4 = 1 MB
#define UNROLL 3                 // 21 = 7 outer x 3 inner, no tail

__device__ __forceinline__ void proc4(const int4& g, const int4& p,
                                      int& tp, int& fp, int& fn) {
    const int gv[4] = {g.x, g.y, g.z, g.w};
    const int pv[4] = {p.x, p.y, p.z, p.w};
#pragma unroll
    for (int k = 0; k < 4; ++k) {
        const int gk = gv[k], pk = pv[k];
        const int valid = (gk != IGNORE_LBL);
        const int eq = (gk == pk);
        const int gin = (gk >= 1) & (gk < N_CLASSES);
        const int pin = (pk >= 1) & (pk < N_CLASSES);
        tp += eq & gin & valid;
        fp += (eq ^ 1) & pin & valid;
        fn += (eq ^ 1) & gin & valid;
    }
}

__global__ __launch_bounds__(THREADS) void iou_count_kernel(
    const int* __restrict__ gt, const int* __restrict__ pred,
    int4* __restrict__ parts) {
    const int b = blockIdx.y;
    const int4* __restrict__ g4 =
        reinterpret_cast<const int4*>(gt) + (size_t)b * VEC_PER_SAMPLE;
    const int4* __restrict__ p4 =
        reinterpret_cast<const int4*>(pred) + (size_t)b * VEC_PER_SAMPLE;

    int i = blockIdx.x * THREADS + threadIdx.x;
    int tp = 0, fp = 0, fn = 0;

#pragma unroll 1
    for (int o = 0; o < 7; ++o) {
        int4 g[UNROLL], p[UNROLL];
#pragma unroll
        for (int k = 0; k < UNROLL; ++k) {
            g[k] = g4[i + k * STRIDE];
            p[k] = p4[i + k * STRIDE];
        }
        __builtin_amdgcn_sched_barrier(0);
#pragma unroll
        for (int k = 0; k < UNROLL; ++k) proc4(g[k], p[k], tp, fp, fn);
        i += UNROLL * STRIDE;
    }

    // wave (64-lane) reduce
#pragma unroll
    for (int off = 32; off > 0; off >>= 1) {
        tp += __shfl_down(tp, off);
        fp += __shfl_down(fp, off);
        fn += __shfl_down(fn, off);
    }

    __shared__ int s_tp[4], s_fp[4], s_fn[4];  // 256 threads = 4 waves
    const int wave = threadIdx.x >> 6;
    const int lane = threadIdx.x & 63;
    if (lane == 0) {
        s_tp[wave] = tp;
        s_fp[wave] = fp;
        s_fn[wave] = fn;
    }
    __syncthreads();
    if (threadIdx.x == 0) {
        int t = 0, f = 0, n = 0;
#pragma unroll
        for (int w = 0; w < 4; ++w) {
            t += s_tp[w];
            f += s_fp[w];
            n += s_fn[w];
        }
        parts[b * BPS + blockIdx.x] = make_int4(t, f, n, 0);
    }
}

// 8 waves, wave w reduces sample w's 256 partials (64 lanes x 4 int4, coalesced)
__global__ __launch_bounds__(512) void iou_final_kernel(
    const int4* __restrict__ parts, float* __restrict__ out) {
    const int w = threadIdx.x >> 6;   // sample
    const int lane = threadIdx.x & 63;

    int t = 0, f = 0, n = 0;
#pragma unroll
    for (int k = 0; k < 4; ++k) {
        const int4 v = parts[w * BPS + k * 64 + lane];
        t += v.x;
        f += v.y;
        n += v.z;
    }
#pragma unroll
    for (int off = 32; off > 0; off >>= 1) {
        t += __shfl_down(t, off);
        f += __shfl_down(f, off);
        n += __shfl_down(n, off);
    }

    __shared__ float jac[BATCH];
    if (lane == 0) {
        const float tp = (float)t, fp = (float)f, fn = (float)n;
        jac[w] = tp / fmaxf(tp + fp + fn, 1e-8f);
    }
    __syncthreads();
    if (threadIdx.x == 0) {
        float s = 0.0f;
#pragma unroll
        for (int b = 0; b < BATCH; ++b) s += jac[b];
        out[0] = s / (float)BATCH;
    }
}

extern "C" void kernel_launch(void* const* d_in, const int* in_sizes, int n_in,
                              void* d_out, int out_size, void* d_ws, size_t ws_size,
                              hipStream_t stream) {
    const int* gt = (const int*)d_in[0];
    const int* pred = (const int*)d_in[1];
    float* out = (float*)d_out;
    int4* parts = (int4*)d_ws;  // 2048 * 16 B = 32 KB

    dim3 grid(BPS, BATCH, 1);
    dim3 block(THREADS, 1, 1);
    iou_count_kernel<<<grid, block, 0, stream>>>(gt, pred, parts);
    iou_final_kernel<<<1, 512, 0, stream>>>(parts, out);
}